// Round 7
// baseline (72.399 us; speedup 1.0000x reference)
//
#include <hip/hip_runtime.h>

#define BB 4
#define NN 8192
#define MM 2048
#define CC 64
#define KK 16

// ---------------------------------------------------------------------------
// Kernel 1: transpose features [B,C,N] -> featsT [B,N,C] so per-neighbor
// feature gathers are contiguous 256B rows.
// ---------------------------------------------------------------------------
__global__ __launch_bounds__(256) void transpose_feats(const float* __restrict__ f,
                                                       float* __restrict__ ft) {
    __shared__ float tile[64][65];
    const int b    = blockIdx.y;
    const int n0   = blockIdx.x * 64;
    const int lane = threadIdx.x & 63;
    const int grp  = threadIdx.x >> 6;  // 0..3
    const float* src = f + (size_t)b * CC * NN;
    float* dst       = ft + (size_t)b * NN * CC;
#pragma unroll
    for (int it = 0; it < 16; ++it) {
        const int c = grp + it * 4;                    // channel
        tile[c][lane] = src[c * NN + n0 + lane];       // coalesced along N
    }
    __syncthreads();
#pragma unroll
    for (int it = 0; it < 16; ++it) {
        const int nl = grp + it * 4;                   // local point
        dst[(size_t)(n0 + nl) * CC + lane] = tile[lane][nl];  // coalesced along C
    }
}

// ---------------------------------------------------------------------------
// Round-7 formula hypothesis: XLA-CPU (FPOpFusion::Fast) contraction of the
// reference expression. All roundings pinned with explicit intrinsics:
//   qq  = fma(qz,qz, fma(qy,qy, qx*qx))        (contracted reduce of squares)
//   pp  = fma(pz,pz, fma(py,py, px*px))
//   dot = fma(qz,pz, fma(qy,py, qx*px))        (Eigen gemm k-loop FMA chain)
//   d   = (qq - 2*dot) + pp                    (2*dot exact; combine invariant)
// Evidence: FMA-dot removes the shared worst flip (r1 vs r2/5/6); squares-FMA
// is the only remaining non-invariant rounding difference.
// ---------------------------------------------------------------------------
__device__ __forceinline__ float sq3(float x, float y, float z) {
    return __fmaf_rn(z, z, __fmaf_rn(y, y, __fmul_rn(x, x)));
}
__device__ __forceinline__ float dist32(float qx, float qy, float qz, float qq,
                                        float px, float py, float pz, float pp) {
    float dot = __fmaf_rn(qz, pz, __fmaf_rn(qy, py, __fmul_rn(qx, px)));
    return __fadd_rn(__fsub_rn(qq, __fmul_rn(2.0f, dot)), pp);
}

// ---------------------------------------------------------------------------
// Kernel 2: per-wave KNN (4 queries/wave).
//   Phase A: per-lane min over its 128 points -> tau = 16th-smallest lane min.
//   Phase B: re-scan, append candidate indices with d <= tau (~18 typical).
//   Phase C: recompute d (same formula), 64-lane bitonic sort on (d, idx)
//            -> top-16, identical set AND order as lax.top_k(-d) stable.
// ---------------------------------------------------------------------------
__global__ __launch_bounds__(256) void knn_group(const float* __restrict__ points,
                                                 const float* __restrict__ newp,
                                                 const float* __restrict__ feat,
                                                 const int fsN, const int fsC,
                                                 float* __restrict__ out) {
    const int wave = threadIdx.x >> 6;
    const int lane = threadIdx.x & 63;
    const int qbase = blockIdx.x * 16 + wave * 4;   // global query id of this wave
    const int b  = qbase / MM;
    const int m0 = qbase % MM;                      // 4 consecutive queries, same batch

    const float* px_ = points + (size_t)b * 3 * NN;
    const float* py_ = px_ + NN;
    const float* pz_ = py_ + NN;
    const float* q_  = newp + (size_t)b * 3 * MM;

    float qx[4], qy[4], qz[4], qq[4];
#pragma unroll
    for (int q = 0; q < 4; ++q) {
        qx[q] = q_[m0 + q];
        qy[q] = q_[MM + m0 + q];
        qz[q] = q_[2 * MM + m0 + q];
        qq[q] = sq3(qx[q], qy[q], qz[q]);
    }

    const float INF = __int_as_float(0x7f800000);

    // ---- Phase A: per-lane min distance over its 128 points (float4 loads) ----
    float m1[4] = {INF, INF, INF, INF};
#pragma unroll 2
    for (int j4 = 0; j4 < 32; ++j4) {
        const int ib = j4 * 256 + lane * 4;
        const float4 vx = *(const float4*)(px_ + ib);
        const float4 vy = *(const float4*)(py_ + ib);
        const float4 vz = *(const float4*)(pz_ + ib);
        const float pxa[4] = {vx.x, vx.y, vx.z, vx.w};
        const float pya[4] = {vy.x, vy.y, vy.z, vy.w};
        const float pza[4] = {vz.x, vz.y, vz.z, vz.w};
#pragma unroll
        for (int e = 0; e < 4; ++e) {
            const float px = pxa[e], py = pya[e], pz = pza[e];
            const float pp = sq3(px, py, pz);
#pragma unroll
            for (int q = 0; q < 4; ++q)
                m1[q] = fminf(m1[q], dist32(qx[q], qy[q], qz[q], qq[q], px, py, pz, pp));
        }
    }

    // ---- tau[q] = 16th smallest of the 64 lane minima (bitonic, values only) ----
    float tau[4];
#pragma unroll
    for (int q = 0; q < 4; ++q) {
        float v = m1[q];
#pragma unroll
        for (int k = 2; k <= 64; k <<= 1) {
#pragma unroll
            for (int j = k >> 1; j > 0; j >>= 1) {
                const float pv = __shfl_xor(v, j, 64);
                const bool keepMin = ((lane & j) == 0) == ((lane & k) == 0);
                v = keepMin ? fminf(v, pv) : fmaxf(v, pv);
            }
        }
        tau[q] = __shfl(v, 15, 64);   // identical formula all phases: no slack
    }

    __shared__ int s_cnt[4][4];
    __shared__ int s_i[4][4][64];
    __shared__ int s_win[4][4][16];
    if (lane < 4) s_cnt[wave][lane] = 0;
    __syncthreads();

    // ---- Phase B: re-scan, append candidate indices with d <= tau ----
#pragma unroll 2
    for (int j4 = 0; j4 < 32; ++j4) {
        const int ib = j4 * 256 + lane * 4;
        const float4 vx = *(const float4*)(px_ + ib);
        const float4 vy = *(const float4*)(py_ + ib);
        const float4 vz = *(const float4*)(pz_ + ib);
        const float pxa[4] = {vx.x, vx.y, vx.z, vx.w};
        const float pya[4] = {vy.x, vy.y, vy.z, vy.w};
        const float pza[4] = {vz.x, vz.y, vz.z, vz.w};
#pragma unroll
        for (int e = 0; e < 4; ++e) {
            const float px = pxa[e], py = pya[e], pz = pza[e];
            const float pp = sq3(px, py, pz);
#pragma unroll
            for (int q = 0; q < 4; ++q) {
                const float d = dist32(qx[q], qy[q], qz[q], qq[q], px, py, pz, pp);
                if (d <= tau[q]) {
                    const int pos = atomicAdd(&s_cnt[wave][q], 1);
                    if (pos < 64) s_i[wave][q][pos] = ib + e;
                }
            }
        }
    }
    __syncthreads();

    // ---- Phase C: recompute d (same formula) + bitonic sort (d, idx) ----
#pragma unroll 1
    for (int q = 0; q < 4; ++q) {
        const int cnt = min(s_cnt[wave][q], 64);
        float d = INF;
        int idx = 0x7fffffff;
        if (lane < cnt) {
            idx = s_i[wave][q][lane];
            const float px = px_[idx], py = py_[idx], pz = pz_[idx];
            d = dist32(qx[q], qy[q], qz[q], qq[q], px, py, pz, sq3(px, py, pz));
        }
#pragma unroll
        for (int k = 2; k <= 64; k <<= 1) {
#pragma unroll
            for (int j = k >> 1; j > 0; j >>= 1) {
                const float pd = __shfl_xor(d, j, 64);
                const int   pi = __shfl_xor(idx, j, 64);
                const bool keepMin = ((lane & j) == 0) == ((lane & k) == 0);
                const bool pLess = (pd < d) || (pd == d && pi < idx);
                if (keepMin ? pLess : !pLess) { d = pd; idx = pi; }
            }
        }
        if (lane < KK) s_win[wave][q][lane] = idx;
    }
    __syncthreads();

    // ---- Write phase: lane = (q2, k); per channel the wave's 64 lanes write
    // 256B contiguous. Recentered coords are single-op f32 subs (bit-safe). ----
    const int q2 = lane >> 4;
    const int kk = lane & 15;
    const int idx = s_win[wave][q2][kk];
    const int m   = m0 + q2;
    const float qxv = q_[m], qyv = q_[MM + m], qzv = q_[2 * MM + m];

    float* ob = out + ((size_t)(b * (3 + CC)) * MM + m0) * KK + lane;
    const size_t chs = (size_t)MM * KK;
    ob[0]       = __fsub_rn(px_[idx], qxv);
    ob[chs]     = __fsub_rn(py_[idx], qyv);
    ob[2 * chs] = __fsub_rn(pz_[idx], qzv);

    const float* fr = feat + (size_t)b * CC * NN + (size_t)idx * fsN;
#pragma unroll 8
    for (int c = 0; c < CC; ++c) {
        ob[(size_t)(3 + c) * chs] = fr[(size_t)c * fsC];
    }
}

extern "C" void kernel_launch(void* const* d_in, const int* in_sizes, int n_in,
                              void* d_out, int out_size, void* d_ws, size_t ws_size,
                              hipStream_t stream) {
    const float* points = (const float*)d_in[0];
    const float* newp   = (const float*)d_in[1];
    const float* feats  = (const float*)d_in[2];
    float* out = (float*)d_out;

    const size_t ftBytes = (size_t)BB * NN * CC * sizeof(float);
    if (ws_size >= ftBytes) {
        float* ft = (float*)d_ws;
        transpose_feats<<<dim3(NN / 64, BB), 256, 0, stream>>>(feats, ft);
        knn_group<<<(BB * MM) / 16, 256, 0, stream>>>(points, newp, ft, CC, 1, out);
    } else {
        // Fallback: gather straight from [B,C,N] (strided) if ws is too small.
        knn_group<<<(BB * MM) / 16, 256, 0, stream>>>(points, newp, feats, 1, NN, out);
    }
}